// Round 22
// baseline (484.617 us; speedup 1.0000x reference)
//
#include <hip/hip_runtime.h>
#include <cstdint>
#include <cstddef>

// Problem constants
#define NU_ 100000
#define NI_ 50000
#define F_ 256
#define H_ 8
#define HD_ 512
#define NE_ 300000
#define SLOPE_ 0.2f

#define MPAD_U 100096   // NU_ rounded up to 128
#define MPAD_I 50048    // NI_ rounded up to 128
#define MT_U (MPAD_U / 128)   // 782
#define MT_I (MPAD_I / 128)   // 391
#define NT_ALL ((MT_U + MT_I) * 8)   // 9384 single-output tiles (4 nt x 2 out per mt)
#define EL_NB (MT_U + MT_I)          // 1173 el/er mini-tiles

#define SCAN_N (NI_ + NU_)
#define SCAN_CHUNK 2048
#define SCAN_NB ((SCAN_N + SCAN_CHUNK - 1) / SCAN_CHUNK)  // 74

// prep kernel grid split: copy | wconv | fold | hist
#define PREP_COPY_U (NU_ * F_ / 2048)          // 12500
#define PREP_COPY_I (NI_ * F_ / 2048)          // 6250
#define PREP_COPY (PREP_COPY_U + PREP_COPY_I)  // 18750
#define PREP_WCONV 2048
#define PREP_FOLD 32
#define PREP_HIST ((2 * NE_ + 255) / 256)      // 2344
#define PREP_NB (PREP_COPY + PREP_WCONV + PREP_FOLD + PREP_HIST)

typedef float f32x4 __attribute__((ext_vector_type(4)));
typedef __bf16 bf16x8 __attribute__((ext_vector_type(8)));
typedef unsigned short u16x8 __attribute__((ext_vector_type(8)));
typedef unsigned short u16x4 __attribute__((ext_vector_type(4)));
typedef unsigned int u32x4 __attribute__((ext_vector_type(4)));

static __device__ __forceinline__ unsigned short f2bf_bits(float f) {
  unsigned u = __float_as_uint(f);
  u += 0x7fffu + ((u >> 16) & 1u);   // RNE
  return (unsigned short)(u >> 16);
}
static __device__ __forceinline__ float bf2f(unsigned short b) {
  return __uint_as_float(((unsigned)b) << 16);
}
// pack 2 f32 -> 2 bf16 (RNE) in one instruction
static __device__ __forceinline__ unsigned cvt_pk_bf16(float lo, float hi) {
  unsigned r;
  asm("v_cvt_pk_bf16_f32 %0, %1, %2" : "=v"(r) : "v"(lo), "v"(hi));
  return r;
}

// async global->LDS, 16B per lane; dest must be wave-uniform base + lane*16
#define GLL16(g, l)                                                        \
  __builtin_amdgcn_global_load_lds(                                        \
      (const __attribute__((address_space(1))) void*)(g),                  \
      (__attribute__((address_space(3))) void*)(l), 16, 0, 0)

// ---------------- prep: h->bf16 copy + wconv + folds(->bf16 wfb) + degree histogram --
// wfb: [0]=user [16][256] rows 0-7 wl_u2i, 8-15 wr_i2u; [1]=item rows 0-7 wl_i2u, 8-15 wr_u2i
__global__ __launch_bounds__(256) void prep_kernel(const float* __restrict__ h_user,
                                                   const float* __restrict__ h_item,
                                                   const float* __restrict__ W0,
                                                   const float* __restrict__ W1,
                                                   const float* __restrict__ W2,
                                                   const float* __restrict__ W3,
                                                   const float* __restrict__ Wd0,
                                                   const float* __restrict__ Wd1,
                                                   const float* __restrict__ a0,
                                                   const float* __restrict__ a1,
                                                   const float* __restrict__ a2,
                                                   const float* __restrict__ a3,
                                                   const int* __restrict__ dst_u2i,
                                                   const int* __restrict__ dst_i2u,
                                                   unsigned short* __restrict__ hb_user,
                                                   unsigned short* __restrict__ hb_item,
                                                   unsigned short* __restrict__ Wt,
                                                   unsigned short* __restrict__ wfb,
                                                   int* __restrict__ deg) {
  int bid = blockIdx.x;
  if (bid < PREP_COPY) {
    // f32 h -> bf16 hb, 8 elems/thread
    bool user = bid < PREP_COPY_U;
    const float* h = user ? h_user : h_item;
    unsigned short* hb = user ? hb_user : hb_item;
    size_t base = (size_t)(user ? bid : bid - PREP_COPY_U) * 2048 + threadIdx.x * 8;
    f32x4 a = *(const f32x4*)&h[base];
    f32x4 b = *(const f32x4*)&h[base + 4];
    u16x8 o;
    o[0] = f2bf_bits(a.x); o[1] = f2bf_bits(a.y); o[2] = f2bf_bits(a.z); o[3] = f2bf_bits(a.w);
    o[4] = f2bf_bits(b.x); o[5] = f2bf_bits(b.y); o[6] = f2bf_bits(b.z); o[7] = f2bf_bits(b.w);
    *(u16x8*)&hb[base] = o;
  } else if (bid < PREP_COPY + PREP_WCONV) {
    // Wt[m][c][f] = bf16(W_m[f][c]) ; m: 0=src_u2i 1=res_u2i 2=src_i2u 3=res_i2u
    int idx = (bid - PREP_COPY) * 256 + threadIdx.x;
    int m = idx >> 17;
    int r = idx & 131071;
    const float* W = (m == 0) ? W0 : (m == 1) ? W1 : (m == 2) ? W2 : W3;
    int f = r & 255, c = r >> 8;
    Wt[idx] = f2bf_bits(W[(size_t)f * HD_ + c]);
  } else if (bid < PREP_COPY + PREP_WCONV + PREP_FOLD) {
    // fold m: 0=wl_u2i(W0,a0) 1=wr_u2i(Wd0,a1) 2=wl_i2u(W2,a2) 3=wr_i2u(Wd1,a3)
    int b = bid - PREP_COPY - PREP_WCONV;
    int m = b >> 3;
    int idx = (b & 7) * 256 + threadIdx.x;
    const float* W = (m == 0) ? W0 : (m == 1) ? Wd0 : (m == 2) ? W2 : Wd1;
    const float* av = (m == 0) ? a0 : (m == 1) ? a1 : (m == 2) ? a2 : a3;
    int f = idx & 255, hh = idx >> 8;
    float acc = 0.f;
#pragma unroll 8
    for (int d = 0; d < 64; ++d) acc += W[(size_t)f * HD_ + hh * 64 + d] * av[hh * 64 + d];
    int buf = (m == 0 || m == 3) ? 0 : 1;
    int rowoff = (m == 1 || m == 3) ? 8 : 0;
    wfb[buf * 4096 + (rowoff + hh) * 256 + f] = f2bf_bits(acc);
  } else {
    int e = (bid - PREP_COPY - PREP_WCONV - PREP_FOLD) * 256 + threadIdx.x;
    if (e < NE_) atomicAdd(&deg[dst_u2i[e]], 1);
    else if (e < 2 * NE_) atomicAdd(&deg[NI_ + dst_i2u[e - NE_]], 1);
  }
}

// ---------------- single-output GEMM tiles + el/er mini-tiles + scan_reduce ----------
// B operand read DIRECTLY global->VGPR (Wt is L2-resident): halves the LDS read pipe
// load (8->4 ds_read_b128 per wave per K-step), the measured per-CU bottleneck.
// A stays LDS-staged (1-deep double buffer, 16KB). vmcnt(2): [A(t),B(t) drained,
// A(t+1) in flight]. LDS 34816B + <=128 VGPR -> 4 blocks/CU.
#define EPITCH 136   // u16 epilogue row pitch (272B, 16B-aligned rows)
#define LOFF(b, r) (((b) * 128 + (r)) * 32)
__global__ __launch_bounds__(256, 4) void gemm2_kernel(const unsigned short* __restrict__ hb_user,
                                                       const unsigned short* __restrict__ hb_item,
                                                       const unsigned short* __restrict__ Wt,
                                                       const unsigned short* __restrict__ wfb,
                                                       unsigned short* __restrict__ fs_u2i,
                                                       unsigned short* __restrict__ fs_i2u,
                                                       unsigned short* __restrict__ res_user,
                                                       unsigned short* __restrict__ res_item,
                                                       const float* __restrict__ bias_u2i,
                                                       const float* __restrict__ bias_i2u,
                                                       float* __restrict__ el_u2i,
                                                       float* __restrict__ er_i2u,
                                                       float* __restrict__ el_i2u,
                                                       float* __restrict__ er_u2i,
                                                       const int* __restrict__ deg,
                                                       int* __restrict__ bsum) {
  __shared__ unsigned short sh[17408];   // 34816 B: A staging 2buf x 128x32 (16KB),
                                         //          epilogue view 128 x 136 (34.8KB)
  int tid = threadIdx.x;
  int lane = tid & 63;
  int wave = tid >> 6;
  int lr = lane & 15;
  int kk = (lane >> 4) * 8;

  if (blockIdx.x >= NT_ALL + EL_NB) {
    // ---- scan_reduce over deg ----
    int* ilds = (int*)sh;
    int base = (blockIdx.x - NT_ALL - EL_NB) * SCAN_CHUNK + tid * 8;
    int sum = 0;
#pragma unroll
    for (int j = 0; j < 8; ++j) sum += (base + j < SCAN_N) ? deg[base + j] : 0;
    ilds[tid] = sum;
    __syncthreads();
    for (int o = 128; o > 0; o >>= 1) {
      if (tid < o) ilds[tid] += ilds[tid + o];
      __syncthreads();
    }
    if (tid == 0) bsum[blockIdx.x - NT_ALL - EL_NB] = ilds[0];
    return;
  }

  if (blockIdx.x >= NT_ALL) {
    // ---- el/er mini-tile: 128 rows x [256,16] wf^T, direct-global, barrier-free ----
    int mt = blockIdx.x - NT_ALL;
    bool user = mt < MT_U;
    int lm = user ? mt : mt - MT_U;
    const unsigned short* A = user ? hb_user : hb_item;
    const unsigned short* wfs = user ? wfb : (wfb + 4096);
    float* elp = user ? el_u2i : el_i2u;
    float* erp = user ? er_i2u : er_u2i;
    int M = user ? NU_ : NI_;
    int bm = lm * 128;
    int mf0 = wave * 2;                       // each wave: 2 m-frags (32 rows)
    f32x4 acc3[2] = {};
#pragma unroll
    for (int t = 0; t < 8; ++t) {
      int ko = kk + t * 32;
      bf16x8 b3 = __builtin_bit_cast(bf16x8, *(const u16x8*)&wfs[(size_t)lr * 256 + ko]);
#pragma unroll
      for (int m = 0; m < 2; ++m) {
        bf16x8 af = __builtin_bit_cast(
            bf16x8, *(const u16x8*)&A[(size_t)(bm + (mf0 + m) * 16 + lr) * 256 + ko]);
        acc3[m] = __builtin_amdgcn_mfma_f32_16x16x32_bf16(af, b3, acc3[m], 0, 0, 0);
      }
    }
    int rg = (lane >> 4) * 4;
#pragma unroll
    for (int m = 0; m < 2; ++m) {
#pragma unroll
      for (int r = 0; r < 4; ++r) {
        int row = bm + (mf0 + m) * 16 + rg + r;
        if (row >= M) continue;
        if (lr < 8) elp[(size_t)row * 8 + lr] = acc3[m][r];
        else        erp[(size_t)row * 8 + lr - 8] = acc3[m][r];
      }
    }
    return;
  }

  // ---- gemm tile ----
  // XCD-aware remap (NT_ALL % 8 == 0): consecutive bids (same A tile) -> same XCD
  int bid;
  {
    constexpr int qq = NT_ALL / 8;   // 1173
    bid = (blockIdx.x & 7) * qq + (blockIdx.x >> 3);
  }
  bool user = bid < MT_U * 8;
  int b = user ? bid : bid - MT_U * 8;
  int mt = b >> 3;
  int sub = b & 7;
  int nt = sub >> 1;
  bool isres = sub & 1;
  const unsigned short* Ab = user ? hb_user : hb_item;
  const unsigned short* Bt = user ? (isres ? Wt + 3 * HD_ * F_ : Wt + 0 * HD_ * F_)
                                  : (isres ? Wt + 1 * HD_ * F_ : Wt + 2 * HD_ * F_);
  unsigned short* dst = user ? (isres ? res_user : fs_u2i)
                             : (isres ? res_item : fs_i2u);
  const float* bias = user ? bias_i2u : bias_u2i;
  int M = user ? NU_ : NI_;

  int wm = wave >> 1, wn = wave & 1;
  int bm = mt * 128, bn = nt * 128;
  f32x4 acc[4][4] = {};
  // T2-swizzled k-slot for A fragment reads (row term reduces to (lr>>1)&3)
  int ksw = ((lane >> 4) ^ ((lr >> 1) & 3)) << 3;

  int r0 = tid >> 2;                              // staged row 0..63 (and +64)
  int c0 = (tid & 3) << 3;                        // linear LDS dest slot (u16 units)
  int cs = (((tid & 3) ^ ((r0 >> 1) & 3)) << 3);  // swizzled global source slot
  const unsigned short* gA = &Ab[(size_t)(bm + r0) * 256 + cs];
  // B fragment base: lane lr reads row bn+wn*64+n*16+lr, 16B at col kk (+t*32)
  const unsigned short* pB = &Bt[(size_t)(bn + wn * 64 + lr) * 256 + kk];

#define STAGE(buf, t)                                                       \
  do {                                                                      \
    int k0_ = (t) * 32;                                                     \
    GLL16(gA + k0_,            &sh[LOFF(buf, r0) + c0]);                    \
    GLL16(gA + k0_ + 64 * 256, &sh[LOFF(buf, r0 + 64) + c0]);               \
  } while (0)

  STAGE(0, 0);
#pragma unroll
  for (int t = 0; t < 8; ++t) {
    // B(t) fragments direct from global (L2-resident weights) -- issued FIRST so the
    // compiler's dependent wait resolves to vmcnt(2), leaving A(t+1) in flight.
    bf16x8 bf[4];
#pragma unroll
    for (int n = 0; n < 4; ++n)
      bf[n] = __builtin_bit_cast(bf16x8, *(const u16x8*)(pB + (size_t)n * 16 * 256 + t * 32));
    if (t < 7) STAGE((t + 1) & 1, t + 1);            // A prefetch stays in flight
    if (t < 7) asm volatile("s_waitcnt vmcnt(2)" ::: "memory");   // A(t),B(t) landed
    else       asm volatile("s_waitcnt vmcnt(0)" ::: "memory");
    __builtin_amdgcn_s_barrier();
    __builtin_amdgcn_sched_barrier(0);
    const int cb = t & 1;
    bf16x8 af[4];
#pragma unroll
    for (int m = 0; m < 4; ++m)
      af[m] = __builtin_bit_cast(bf16x8,
          *(const u16x8*)&sh[LOFF(cb, wm * 64 + m * 16 + lr) + ksw]);
    // SWAPPED operand order: D reg = 4 consecutive cols of one row
#pragma unroll
    for (int m = 0; m < 4; ++m)
#pragma unroll
      for (int n = 0; n < 4; ++n)
        acc[m][n] = __builtin_amdgcn_mfma_f32_16x16x32_bf16(bf[n], af[m], acc[m][n], 0, 0, 0);
    __builtin_amdgcn_sched_barrier(0);
    __builtin_amdgcn_s_barrier();                    // reads done before next overwrite
  }
#undef STAGE

  int rg = (lane >> 4) * 4;
  f32x4 bsv[4];
#pragma unroll
  for (int n = 0; n < 4; ++n) {
    if (isres) bsv[n] = *(const f32x4*)&bias[bn + wn * 64 + n * 16 + rg];
    else       bsv[n] = f32x4{0.f, 0.f, 0.f, 0.f};
  }

  // ---- LDS-transposed coalesced epilogue (sh as [128][EPITCH] u16) ----
  __syncthreads();   // all waves done with staging LDS
#pragma unroll
  for (int m = 0; m < 4; ++m) {
    int rowl = wm * 64 + m * 16 + lr;
#pragma unroll
    for (int n = 0; n < 4; ++n) {
      int coll = wn * 64 + n * 16 + rg;
      uint2 v;
      v.x = cvt_pk_bf16(acc[m][n][0] + bsv[n].x, acc[m][n][1] + bsv[n].y);
      v.y = cvt_pk_bf16(acc[m][n][2] + bsv[n].z, acc[m][n][3] + bsv[n].w);
      *(uint2*)&sh[rowl * EPITCH + coll] = v;
    }
  }
  __syncthreads();
#pragma unroll
  for (int p = 0; p < 8; ++p) {
    int id = tid + p * 256;
    int rowl = id >> 4, c16 = (id & 15) * 8;     // 16B chunk (8 u16)
    int growl = bm + rowl;
    if (growl < M)
      *(u32x4*)&dst[(size_t)growl * HD_ + bn + c16] = *(const u32x4*)&sh[rowl * EPITCH + c16];
  }
}
#undef LOFF

// ---------------- scan_apply (self-scans the 74 block sums) --------------------------
__global__ __launch_bounds__(256) void scan_apply_kernel(const int* __restrict__ deg,
                                                         const int* __restrict__ bsum,
                                                         int* __restrict__ rowstart,
                                                         int* __restrict__ cursor) {
  __shared__ int sb[128];
  __shared__ int lds[256];
  int tid = threadIdx.x;
  if (tid < 128) sb[tid] = (tid < SCAN_NB) ? bsum[tid] : 0;
  __syncthreads();
  for (int o = 1; o < 128; o <<= 1) {
    int t = (tid < 128 && tid >= o) ? sb[tid - o] : 0;
    __syncthreads();
    if (tid < 128) sb[tid] += t;
    __syncthreads();
  }
  int blockpref = (blockIdx.x == 0) ? 0 : sb[blockIdx.x - 1];
  int base = blockIdx.x * SCAN_CHUNK + tid * 8;
  int v[8];
  int sum = 0;
#pragma unroll
  for (int j = 0; j < 8; ++j) {
    v[j] = (base + j < SCAN_N) ? deg[base + j] : 0;
    sum += v[j];
  }
  lds[tid] = sum;
  __syncthreads();
  for (int o = 1; o < 256; o <<= 1) {
    int t = (tid >= o) ? lds[tid - o] : 0;
    __syncthreads();
    lds[tid] += t;
    __syncthreads();
  }
  int run = blockpref + lds[tid] - sum;
#pragma unroll
  for (int j = 0; j < 8; ++j) {
    if (base + j < SCAN_N) { rowstart[base + j] = run; cursor[base + j] = run; }
    run += v[j];
  }
  if (blockIdx.x == 0 && tid == 0) rowstart[SCAN_N] = 2 * NE_;
}

// ---------------- bin: scatter source node ids into CSR slots ----------------
__global__ __launch_bounds__(256) void bin_kernel(const int* __restrict__ src_u2i,
                                                  const int* __restrict__ dst_u2i,
                                                  const int* __restrict__ src_i2u,
                                                  const int* __restrict__ dst_i2u,
                                                  int* __restrict__ cursor,
                                                  int* __restrict__ ssrc) {
  int e = blockIdx.x * 256 + threadIdx.x;
  int de, se;
  if (e < NE_) { de = dst_u2i[e]; se = src_u2i[e]; }
  else if (e < 2 * NE_) { de = NI_ + dst_i2u[e - NE_]; se = src_i2u[e - NE_]; }
  else return;
  int pos = atomicAdd(&cursor[de], 1);
  ssrc[pos] = se;
}

// ---------------- fused accum: online softmax + weighted fs gather + residual --------
__global__ __launch_bounds__(256) void accum_kernel(const int* __restrict__ rowstart,
                                                    const int* __restrict__ ssrc,
                                                    const float* __restrict__ el_u2i,
                                                    const float* __restrict__ el_i2u,
                                                    const float* __restrict__ er_u2i,
                                                    const float* __restrict__ er_i2u,
                                                    const unsigned short* __restrict__ fs_u2i,
                                                    const unsigned short* __restrict__ fs_i2u,
                                                    const unsigned short* __restrict__ res_user,
                                                    const unsigned short* __restrict__ res_item,
                                                    float* __restrict__ out_item,
                                                    float* __restrict__ out_user) {
  int n = blockIdx.x * 4 + (threadIdx.x >> 6);
  int lane = threadIdx.x & 63;
  bool item = n < NI_;
  int ln = item ? n : n - NI_;
  const unsigned short* res = item ? res_item : res_user;
  float* out = (item ? out_item : out_user) + (size_t)ln * HD_;
  int r0 = rowstart[n], r1 = rowstart[n + 1];
  float acc[8] = {};
  if (r0 < r1) {
    const float* el = item ? el_u2i : el_i2u;
    const float* er = item ? er_u2i : er_i2u;
    const unsigned short* fs = item ? fs_u2i : fs_i2u;
    int hh = lane >> 3;
    float erh = er[(size_t)ln * 8 + hh];
    float m = -3.0e38f, s = 0.f;
    int k = r0;
    for (; k + 2 <= r1; k += 2) {
      int s0 = ssrc[k], s1 = ssrc[k + 1];
      float e0 = el[(size_t)s0 * 8 + hh] + erh;
      float e1 = el[(size_t)s1 * 8 + hh] + erh;
      e0 = e0 > 0.f ? e0 : SLOPE_ * e0;
      e1 = e1 > 0.f ? e1 : SLOPE_ * e1;
      u16x8 v0 = *(const u16x8*)&fs[(size_t)s0 * HD_ + lane * 8];
      u16x8 v1 = *(const u16x8*)&fs[(size_t)s1 * HD_ + lane * 8];
      float mm = fmaxf(e0, e1);
      if (mm > m) {
        float r = __expf(m - mm);
        s *= r;
#pragma unroll
        for (int j = 0; j < 8; ++j) acc[j] *= r;
        m = mm;
      }
      float x0 = __expf(e0 - m), x1 = __expf(e1 - m);
      s += x0 + x1;
#pragma unroll
      for (int j = 0; j < 8; ++j)
        acc[j] += x0 * bf2f((unsigned short)v0[j]) + x1 * bf2f((unsigned short)v1[j]);
    }
    if (k < r1) {
      int s0 = ssrc[k];
      float e0 = el[(size_t)s0 * 8 + hh] + erh;
      e0 = e0 > 0.f ? e0 : SLOPE_ * e0;
      u16x8 v0 = *(const u16x8*)&fs[(size_t)s0 * HD_ + lane * 8];
      if (e0 > m) {
        float r = __expf(m - e0);
        s *= r;
#pragma unroll
        for (int j = 0; j < 8; ++j) acc[j] *= r;
        m = e0;
      }
      float x0 = __expf(e0 - m);
      s += x0;
#pragma unroll
      for (int j = 0; j < 8; ++j) acc[j] += x0 * bf2f((unsigned short)v0[j]);
    }
    float inv = 1.f / s;
#pragma unroll
    for (int j = 0; j < 8; ++j) acc[j] *= inv;
  }
  u16x8 rv = *(const u16x8*)&res[(size_t)ln * HD_ + lane * 8];
  f32x4 o0, o1;
#pragma unroll
  for (int j = 0; j < 4; ++j) {
    o0[j] = acc[j] + bf2f((unsigned short)rv[j]);
    o1[j] = acc[4 + j] + bf2f((unsigned short)rv[4 + j]);
  }
  float* op = out + lane * 8;
  *(f32x4*)op = o0;
  *(f32x4*)(op + 4) = o1;
}

// =====================================================================================
extern "C" void kernel_launch(void* const* d_in, const int* in_sizes, int n_in,
                              void* d_out, int out_size, void* d_ws, size_t ws_size,
                              hipStream_t stream) {
  const float* h_user    = (const float*)d_in[0];
  const float* h_item    = (const float*)d_in[1];
  const int*   src_u2i   = (const int*)d_in[2];
  const int*   dst_u2i   = (const int*)d_in[3];
  const int*   src_i2u   = (const int*)d_in[4];
  const int*   dst_i2u   = (const int*)d_in[5];
  const float* W_src_u2i = (const float*)d_in[6];
  const float* W_dst_u2i = (const float*)d_in[7];
  const float* al_u2i    = (const float*)d_in[8];
  const float* ar_u2i    = (const float*)d_in[9];
  const float* bias_u2i  = (const float*)d_in[10];
  const float* W_res_u2i = (const float*)d_in[11];
  const float* W_src_i2u = (const float*)d_in[12];
  const float* W_dst_i2u = (const float*)d_in[13];
  const float* al_i2u    = (const float*)d_in[14];
  const float* ar_i2u    = (const float*)d_in[15];
  const float* bias_i2u  = (const float*)d_in[16];
  const float* W_res_i2u = (const float*)d_in[17];

  float* out_user = (float*)d_out;                       // [NU,512]
  float* out_item = (float*)d_out + (size_t)NU_ * HD_;   // [NI,512]

  char* ws = (char*)d_ws;
  size_t off = 0;
  auto take = [&](size_t bytes) -> char* {
    char* p = ws + off;
    off += (bytes + 255) & ~(size_t)255;
    return p;
  };
  unsigned short* fs_u2i   = (unsigned short*)take((size_t)NU_ * HD_ * 2);
  unsigned short* fs_i2u   = (unsigned short*)take((size_t)NI_ * HD_ * 2);
  unsigned short* res_user = (unsigned short*)take((size_t)NU_ * HD_ * 2);
  unsigned short* res_item = (unsigned short*)take((size_t)NI_ * HD_ * 2);
  unsigned short* hb_user  = (unsigned short*)take((size_t)MPAD_U * F_ * 2);
  unsigned short* hb_item  = (unsigned short*)take((size_t)MPAD_I * F_ * 2);
  // Wt: [0]=src_u2i [1]=res_u2i [2]=src_i2u [3]=res_i2u, each [512][256] bf16
  unsigned short* Wt  = (unsigned short*)take((size_t)4 * HD_ * F_ * 2);
  unsigned short* wfb = (unsigned short*)take((size_t)2 * 16 * F_ * 2);
  float* el_u2i = (float*)take((size_t)NU_ * 8 * 4);
  float* er_i2u = (float*)take((size_t)NU_ * 8 * 4);
  float* el_i2u = (float*)take((size_t)NI_ * 8 * 4);
  float* er_u2i = (float*)take((size_t)NI_ * 8 * 4);
  int* deg_all      = (int*)take((size_t)SCAN_N * 4);        // zeroed
  int* rowstart_all = (int*)take((size_t)(SCAN_N + 1) * 4);
  int* cursor_all   = (int*)take((size_t)SCAN_N * 4);
  int* bsum         = (int*)take((size_t)128 * 4);
  int* ssrc         = (int*)take((size_t)2 * NE_ * 4);

  hipMemsetAsync(deg_all, 0, (size_t)SCAN_N * 4, stream);

  // copy + wconv + folds + degree histogram (one launch)
  prep_kernel<<<PREP_NB, 256, 0, stream>>>(h_user, h_item,
                                           W_src_u2i, W_res_u2i, W_src_i2u, W_res_i2u,
                                           W_dst_u2i, W_dst_i2u,
                                           al_u2i, ar_u2i, al_i2u, ar_i2u,
                                           dst_u2i, dst_i2u,
                                           hb_user, hb_item, Wt, wfb, deg_all);

  // single-output GEMM tiles + el/er mini-tiles + scan_reduce tail
  gemm2_kernel<<<NT_ALL + EL_NB + SCAN_NB, 256, 0, stream>>>(
      hb_user, hb_item, Wt, wfb,
      fs_u2i, fs_i2u, res_user, res_item,
      bias_u2i, bias_i2u,
      el_u2i, er_i2u, el_i2u, er_u2i,
      deg_all, bsum);

  // CSR: scan + bin
  scan_apply_kernel<<<SCAN_NB, 256, 0, stream>>>(deg_all, bsum, rowstart_all, cursor_all);
  constexpr int EB2 = (2 * NE_ + 255) / 256;
  bin_kernel<<<EB2, 256, 0, stream>>>(src_u2i, dst_u2i, src_i2u, dst_i2u, cursor_all, ssrc);

  // fused online-softmax gather-accumulate + residual, write-only out
  accum_kernel<<<SCAN_N / 4, 256, 0, stream>>>(rowstart_all, ssrc,
                                               el_u2i, el_i2u, er_u2i, er_i2u,
                                               fs_u2i, fs_i2u, res_user, res_item,
                                               out_item, out_user);
}

// Round 23
// 459.251 us; speedup vs baseline: 1.0552x; 1.0552x over previous
//
#include <hip/hip_runtime.h>
#include <cstdint>
#include <cstddef>

// Problem constants
#define NU_ 100000
#define NI_ 50000
#define F_ 256
#define H_ 8
#define HD_ 512
#define NE_ 300000
#define SLOPE_ 0.2f

#define MPAD_U 100096   // NU_ rounded up to 128
#define MPAD_I 50048    // NI_ rounded up to 128
#define MT_U (MPAD_U / 128)   // 782
#define MT_I (MPAD_I / 128)   // 391
#define NT_ALL ((MT_U + MT_I) * 8)   // 9384 single-output tiles (4 nt x 2 out per mt)
#define EL_NB (MT_U + MT_I)          // 1173 el/er mini-tiles

#define SCAN_N (NI_ + NU_)
#define SCAN_CHUNK 2048
#define SCAN_NB ((SCAN_N + SCAN_CHUNK - 1) / SCAN_CHUNK)  // 74

// prep kernel grid split: copy | wconv | fold | hist
#define PREP_COPY_U (NU_ * F_ / 2048)          // 12500
#define PREP_COPY_I (NI_ * F_ / 2048)          // 6250
#define PREP_COPY (PREP_COPY_U + PREP_COPY_I)  // 18750
#define PREP_WCONV 2048
#define PREP_FOLD 32
#define PREP_HIST ((2 * NE_ + 255) / 256)      // 2344
#define PREP_NB (PREP_COPY + PREP_WCONV + PREP_FOLD + PREP_HIST)

typedef float f32x4 __attribute__((ext_vector_type(4)));
typedef __bf16 bf16x8 __attribute__((ext_vector_type(8)));
typedef unsigned short u16x8 __attribute__((ext_vector_type(8)));
typedef unsigned short u16x4 __attribute__((ext_vector_type(4)));
typedef unsigned int u32x4 __attribute__((ext_vector_type(4)));

static __device__ __forceinline__ unsigned short f2bf_bits(float f) {
  unsigned u = __float_as_uint(f);
  u += 0x7fffu + ((u >> 16) & 1u);   // RNE
  return (unsigned short)(u >> 16);
}
static __device__ __forceinline__ float bf2f(unsigned short b) {
  return __uint_as_float(((unsigned)b) << 16);
}
// pack 2 f32 -> 2 bf16 (RNE) in one instruction
static __device__ __forceinline__ unsigned cvt_pk_bf16(float lo, float hi) {
  unsigned r;
  asm("v_cvt_pk_bf16_f32 %0, %1, %2" : "=v"(r) : "v"(lo), "v"(hi));
  return r;
}

// async global->LDS, 16B per lane; dest must be wave-uniform base + lane*16
#define GLL16(g, l)                                                        \
  __builtin_amdgcn_global_load_lds(                                        \
      (const __attribute__((address_space(1))) void*)(g),                  \
      (__attribute__((address_space(3))) void*)(l), 16, 0, 0)

// ---------------- prep: h->bf16 copy + wconv + folds(->bf16 wfb) + degree histogram --
// wfb: [0]=user [16][256] rows 0-7 wl_u2i, 8-15 wr_i2u; [1]=item rows 0-7 wl_i2u, 8-15 wr_u2i
__global__ __launch_bounds__(256) void prep_kernel(const float* __restrict__ h_user,
                                                   const float* __restrict__ h_item,
                                                   const float* __restrict__ W0,
                                                   const float* __restrict__ W1,
                                                   const float* __restrict__ W2,
                                                   const float* __restrict__ W3,
                                                   const float* __restrict__ Wd0,
                                                   const float* __restrict__ Wd1,
                                                   const float* __restrict__ a0,
                                                   const float* __restrict__ a1,
                                                   const float* __restrict__ a2,
                                                   const float* __restrict__ a3,
                                                   const int* __restrict__ dst_u2i,
                                                   const int* __restrict__ dst_i2u,
                                                   unsigned short* __restrict__ hb_user,
                                                   unsigned short* __restrict__ hb_item,
                                                   unsigned short* __restrict__ Wt,
                                                   unsigned short* __restrict__ wfb,
                                                   int* __restrict__ deg) {
  int bid = blockIdx.x;
  if (bid < PREP_COPY) {
    // f32 h -> bf16 hb, 8 elems/thread
    bool user = bid < PREP_COPY_U;
    const float* h = user ? h_user : h_item;
    unsigned short* hb = user ? hb_user : hb_item;
    size_t base = (size_t)(user ? bid : bid - PREP_COPY_U) * 2048 + threadIdx.x * 8;
    f32x4 a = *(const f32x4*)&h[base];
    f32x4 b = *(const f32x4*)&h[base + 4];
    u16x8 o;
    o[0] = f2bf_bits(a.x); o[1] = f2bf_bits(a.y); o[2] = f2bf_bits(a.z); o[3] = f2bf_bits(a.w);
    o[4] = f2bf_bits(b.x); o[5] = f2bf_bits(b.y); o[6] = f2bf_bits(b.z); o[7] = f2bf_bits(b.w);
    *(u16x8*)&hb[base] = o;
  } else if (bid < PREP_COPY + PREP_WCONV) {
    // Wt[m][c][f] = bf16(W_m[f][c]) ; m: 0=src_u2i 1=res_u2i 2=src_i2u 3=res_i2u
    int idx = (bid - PREP_COPY) * 256 + threadIdx.x;
    int m = idx >> 17;
    int r = idx & 131071;
    const float* W = (m == 0) ? W0 : (m == 1) ? W1 : (m == 2) ? W2 : W3;
    int f = r & 255, c = r >> 8;
    Wt[idx] = f2bf_bits(W[(size_t)f * HD_ + c]);
  } else if (bid < PREP_COPY + PREP_WCONV + PREP_FOLD) {
    // fold m: 0=wl_u2i(W0,a0) 1=wr_u2i(Wd0,a1) 2=wl_i2u(W2,a2) 3=wr_i2u(Wd1,a3)
    int b = bid - PREP_COPY - PREP_WCONV;
    int m = b >> 3;
    int idx = (b & 7) * 256 + threadIdx.x;
    const float* W = (m == 0) ? W0 : (m == 1) ? Wd0 : (m == 2) ? W2 : Wd1;
    const float* av = (m == 0) ? a0 : (m == 1) ? a1 : (m == 2) ? a2 : a3;
    int f = idx & 255, hh = idx >> 8;
    float acc = 0.f;
#pragma unroll 8
    for (int d = 0; d < 64; ++d) acc += W[(size_t)f * HD_ + hh * 64 + d] * av[hh * 64 + d];
    int buf = (m == 0 || m == 3) ? 0 : 1;
    int rowoff = (m == 1 || m == 3) ? 8 : 0;
    wfb[buf * 4096 + (rowoff + hh) * 256 + f] = f2bf_bits(acc);
  } else {
    int e = (bid - PREP_COPY - PREP_WCONV - PREP_FOLD) * 256 + threadIdx.x;
    if (e < NE_) atomicAdd(&deg[dst_u2i[e]], 1);
    else if (e < 2 * NE_) atomicAdd(&deg[NI_ + dst_i2u[e - NE_]], 1);
  }
}

// ---------------- single-output GEMM tiles + el/er mini-tiles + scan_reduce ----------
// 2-deep prefetch, 3 LDS staging buffers: tiles t+1,t+2 stay in flight (vmcnt(8)) so
// each tile's loads get two K-steps of compute time to land. LDS 48KB -> 3 blocks/CU.
#define EPITCH 136   // u16 epilogue row pitch (272B, 16B-aligned rows)
#define LOFF(b, m, r) ((((b) * 2 + (m)) * 128 + (r)) * 32)
__global__ __launch_bounds__(256) void gemm2_kernel(const unsigned short* __restrict__ hb_user,
                                                    const unsigned short* __restrict__ hb_item,
                                                    const unsigned short* __restrict__ Wt,
                                                    const unsigned short* __restrict__ wfb,
                                                    unsigned short* __restrict__ fs_u2i,
                                                    unsigned short* __restrict__ fs_i2u,
                                                    unsigned short* __restrict__ res_user,
                                                    unsigned short* __restrict__ res_item,
                                                    const float* __restrict__ bias_u2i,
                                                    const float* __restrict__ bias_i2u,
                                                    float* __restrict__ el_u2i,
                                                    float* __restrict__ er_i2u,
                                                    float* __restrict__ el_i2u,
                                                    float* __restrict__ er_u2i,
                                                    const int* __restrict__ deg,
                                                    int* __restrict__ bsum) {
  __shared__ unsigned short sh[24576];   // 49152 B: staging 3buf x 2mat x 128x32
                                         //          epilogue view 128 x 136 (34.8KB)
  int tid = threadIdx.x;
  int lane = tid & 63;
  int wave = tid >> 6;
  int lr = lane & 15;
  int kk = (lane >> 4) * 8;

  if (blockIdx.x >= NT_ALL + EL_NB) {
    // ---- scan_reduce over deg ----
    int* ilds = (int*)sh;
    int base = (blockIdx.x - NT_ALL - EL_NB) * SCAN_CHUNK + tid * 8;
    int sum = 0;
#pragma unroll
    for (int j = 0; j < 8; ++j) sum += (base + j < SCAN_N) ? deg[base + j] : 0;
    ilds[tid] = sum;
    __syncthreads();
    for (int o = 128; o > 0; o >>= 1) {
      if (tid < o) ilds[tid] += ilds[tid + o];
      __syncthreads();
    }
    if (tid == 0) bsum[blockIdx.x - NT_ALL - EL_NB] = ilds[0];
    return;
  }

  if (blockIdx.x >= NT_ALL) {
    // ---- el/er mini-tile: 128 rows x [256,16] wf^T, direct-global, barrier-free ----
    int mt = blockIdx.x - NT_ALL;
    bool user = mt < MT_U;
    int lm = user ? mt : mt - MT_U;
    const unsigned short* A = user ? hb_user : hb_item;
    const unsigned short* wfs = user ? wfb : (wfb + 4096);
    float* elp = user ? el_u2i : el_i2u;
    float* erp = user ? er_i2u : er_u2i;
    int M = user ? NU_ : NI_;
    int bm = lm * 128;
    int mf0 = wave * 2;                       // each wave: 2 m-frags (32 rows)
    f32x4 acc3[2] = {};
#pragma unroll
    for (int t = 0; t < 8; ++t) {
      int ko = kk + t * 32;
      bf16x8 b3 = __builtin_bit_cast(bf16x8, *(const u16x8*)&wfs[(size_t)lr * 256 + ko]);
#pragma unroll
      for (int m = 0; m < 2; ++m) {
        bf16x8 af = __builtin_bit_cast(
            bf16x8, *(const u16x8*)&A[(size_t)(bm + (mf0 + m) * 16 + lr) * 256 + ko]);
        acc3[m] = __builtin_amdgcn_mfma_f32_16x16x32_bf16(af, b3, acc3[m], 0, 0, 0);
      }
    }
    int rg = (lane >> 4) * 4;
#pragma unroll
    for (int m = 0; m < 2; ++m) {
#pragma unroll
      for (int r = 0; r < 4; ++r) {
        int row = bm + (mf0 + m) * 16 + rg + r;
        if (row >= M) continue;
        if (lr < 8) elp[(size_t)row * 8 + lr] = acc3[m][r];
        else        erp[(size_t)row * 8 + lr - 8] = acc3[m][r];
      }
    }
    return;
  }

  // ---- gemm tile ----
  // XCD-aware remap (NT_ALL % 8 == 0): consecutive bids (same A tile) -> same XCD
  int bid;
  {
    constexpr int qq = NT_ALL / 8;   // 1173
    bid = (blockIdx.x & 7) * qq + (blockIdx.x >> 3);
  }
  bool user = bid < MT_U * 8;
  int b = user ? bid : bid - MT_U * 8;
  int mt = b >> 3;
  int sub = b & 7;
  int nt = sub >> 1;
  bool isres = sub & 1;
  const unsigned short* Ab = user ? hb_user : hb_item;
  const unsigned short* Bt = user ? (isres ? Wt + 3 * HD_ * F_ : Wt + 0 * HD_ * F_)
                                  : (isres ? Wt + 1 * HD_ * F_ : Wt + 2 * HD_ * F_);
  unsigned short* dst = user ? (isres ? res_user : fs_u2i)
                             : (isres ? res_item : fs_i2u);
  const float* bias = user ? bias_i2u : bias_u2i;
  int M = user ? NU_ : NI_;

  int wm = wave >> 1, wn = wave & 1;
  int bm = mt * 128, bn = nt * 128;
  f32x4 acc[4][4] = {};
  // T2-swizzled k-slot for fragment reads (row term reduces to (lr>>1)&3)
  int ksw = ((lane >> 4) ^ ((lr >> 1) & 3)) << 3;

  int r0 = tid >> 2;                              // staged row 0..63 (and +64)
  int c0 = (tid & 3) << 3;                        // linear LDS dest slot (u16 units)
  int cs = (((tid & 3) ^ ((r0 >> 1) & 3)) << 3);  // swizzled global source slot
  const unsigned short* gA = &Ab[(size_t)(bm + r0) * 256 + cs];
  const unsigned short* gB = &Bt[(size_t)(bn + r0) * 256 + cs];

#define STAGE(buf, t)                                                       \
  do {                                                                      \
    int k0_ = (t) * 32;                                                     \
    GLL16(gA + k0_,            &sh[LOFF(buf, 0, r0) + c0]);                 \
    GLL16(gA + k0_ + 64 * 256, &sh[LOFF(buf, 0, r0 + 64) + c0]);            \
    GLL16(gB + k0_,            &sh[LOFF(buf, 1, r0) + c0]);                 \
    GLL16(gB + k0_ + 64 * 256, &sh[LOFF(buf, 1, r0 + 64) + c0]);            \
  } while (0)

  STAGE(0, 0);
  STAGE(1, 1);
#pragma unroll
  for (int t = 0; t < 8; ++t) {
    if (t + 2 < 8) STAGE((t + 2) % 3, t + 2);        // 2-deep prefetch stays in flight
    if (t < 6)       asm volatile("s_waitcnt vmcnt(8)" ::: "memory");  // t landed; t+1,t+2 in flight
    else if (t == 6) asm volatile("s_waitcnt vmcnt(4)" ::: "memory");  // t landed; 7 in flight
    else             asm volatile("s_waitcnt vmcnt(0)" ::: "memory");
    __builtin_amdgcn_s_barrier();
    __builtin_amdgcn_sched_barrier(0);
    const int cb = t % 3;
    bf16x8 af[4], bf[4];
#pragma unroll
    for (int m = 0; m < 4; ++m)
      af[m] = __builtin_bit_cast(bf16x8,
          *(const u16x8*)&sh[LOFF(cb, 0, wm * 64 + m * 16 + lr) + ksw]);
#pragma unroll
    for (int n = 0; n < 4; ++n)
      bf[n] = __builtin_bit_cast(bf16x8,
          *(const u16x8*)&sh[LOFF(cb, 1, wn * 64 + n * 16 + lr) + ksw]);
    // SWAPPED operand order: D reg = 4 consecutive cols of one row
#pragma unroll
    for (int m = 0; m < 4; ++m)
#pragma unroll
      for (int n = 0; n < 4; ++n)
        acc[m][n] = __builtin_amdgcn_mfma_f32_16x16x32_bf16(bf[n], af[m], acc[m][n], 0, 0, 0);
    __builtin_amdgcn_sched_barrier(0);
    __builtin_amdgcn_s_barrier();                    // reads done before next overwrite
  }
#undef STAGE

  int rg = (lane >> 4) * 4;
  f32x4 bsv[4];
#pragma unroll
  for (int n = 0; n < 4; ++n) {
    if (isres) bsv[n] = *(const f32x4*)&bias[bn + wn * 64 + n * 16 + rg];
    else       bsv[n] = f32x4{0.f, 0.f, 0.f, 0.f};
  }

  // ---- LDS-transposed coalesced epilogue (sh as [128][EPITCH] u16) ----
  __syncthreads();   // all waves done with staging LDS
#pragma unroll
  for (int m = 0; m < 4; ++m) {
    int rowl = wm * 64 + m * 16 + lr;
#pragma unroll
    for (int n = 0; n < 4; ++n) {
      int coll = wn * 64 + n * 16 + rg;
      uint2 v;
      v.x = cvt_pk_bf16(acc[m][n][0] + bsv[n].x, acc[m][n][1] + bsv[n].y);
      v.y = cvt_pk_bf16(acc[m][n][2] + bsv[n].z, acc[m][n][3] + bsv[n].w);
      *(uint2*)&sh[rowl * EPITCH + coll] = v;
    }
  }
  __syncthreads();
#pragma unroll
  for (int p = 0; p < 8; ++p) {
    int id = tid + p * 256;
    int rowl = id >> 4, c16 = (id & 15) * 8;     // 16B chunk (8 u16)
    int growl = bm + rowl;
    if (growl < M)
      *(u32x4*)&dst[(size_t)growl * HD_ + bn + c16] = *(const u32x4*)&sh[rowl * EPITCH + c16];
  }
}
#undef LOFF

// ---------------- scan_apply (self-scans the 74 block sums) --------------------------
__global__ __launch_bounds__(256) void scan_apply_kernel(const int* __restrict__ deg,
                                                         const int* __restrict__ bsum,
                                                         int* __restrict__ rowstart,
                                                         int* __restrict__ cursor) {
  __shared__ int sb[128];
  __shared__ int lds[256];
  int tid = threadIdx.x;
  if (tid < 128) sb[tid] = (tid < SCAN_NB) ? bsum[tid] : 0;
  __syncthreads();
  for (int o = 1; o < 128; o <<= 1) {
    int t = (tid < 128 && tid >= o) ? sb[tid - o] : 0;
    __syncthreads();
    if (tid < 128) sb[tid] += t;
    __syncthreads();
  }
  int blockpref = (blockIdx.x == 0) ? 0 : sb[blockIdx.x - 1];
  int base = blockIdx.x * SCAN_CHUNK + tid * 8;
  int v[8];
  int sum = 0;
#pragma unroll
  for (int j = 0; j < 8; ++j) {
    v[j] = (base + j < SCAN_N) ? deg[base + j] : 0;
    sum += v[j];
  }
  lds[tid] = sum;
  __syncthreads();
  for (int o = 1; o < 256; o <<= 1) {
    int t = (tid >= o) ? lds[tid - o] : 0;
    __syncthreads();
    lds[tid] += t;
    __syncthreads();
  }
  int run = blockpref + lds[tid] - sum;
#pragma unroll
  for (int j = 0; j < 8; ++j) {
    if (base + j < SCAN_N) { rowstart[base + j] = run; cursor[base + j] = run; }
    run += v[j];
  }
  if (blockIdx.x == 0 && tid == 0) rowstart[SCAN_N] = 2 * NE_;
}

// ---------------- bin: scatter source node ids into CSR slots ----------------
__global__ __launch_bounds__(256) void bin_kernel(const int* __restrict__ src_u2i,
                                                  const int* __restrict__ dst_u2i,
                                                  const int* __restrict__ src_i2u,
                                                  const int* __restrict__ dst_i2u,
                                                  int* __restrict__ cursor,
                                                  int* __restrict__ ssrc) {
  int e = blockIdx.x * 256 + threadIdx.x;
  int de, se;
  if (e < NE_) { de = dst_u2i[e]; se = src_u2i[e]; }
  else if (e < 2 * NE_) { de = NI_ + dst_i2u[e - NE_]; se = src_i2u[e - NE_]; }
  else return;
  int pos = atomicAdd(&cursor[de], 1);
  ssrc[pos] = se;
}

// ---------------- fused accum: online softmax + weighted fs gather + residual --------
__global__ __launch_bounds__(256) void accum_kernel(const int* __restrict__ rowstart,
                                                    const int* __restrict__ ssrc,
                                                    const float* __restrict__ el_u2i,
                                                    const float* __restrict__ el_i2u,
                                                    const float* __restrict__ er_u2i,
                                                    const float* __restrict__ er_i2u,
                                                    const unsigned short* __restrict__ fs_u2i,
                                                    const unsigned short* __restrict__ fs_i2u,
                                                    const unsigned short* __restrict__ res_user,
                                                    const unsigned short* __restrict__ res_item,
                                                    float* __restrict__ out_item,
                                                    float* __restrict__ out_user) {
  int n = blockIdx.x * 4 + (threadIdx.x >> 6);
  int lane = threadIdx.x & 63;
  bool item = n < NI_;
  int ln = item ? n : n - NI_;
  const unsigned short* res = item ? res_item : res_user;
  float* out = (item ? out_item : out_user) + (size_t)ln * HD_;
  int r0 = rowstart[n], r1 = rowstart[n + 1];
  float acc[8] = {};
  if (r0 < r1) {
    const float* el = item ? el_u2i : el_i2u;
    const float* er = item ? er_u2i : er_i2u;
    const unsigned short* fs = item ? fs_u2i : fs_i2u;
    int hh = lane >> 3;
    float erh = er[(size_t)ln * 8 + hh];
    float m = -3.0e38f, s = 0.f;
    int k = r0;
    for (; k + 2 <= r1; k += 2) {
      int s0 = ssrc[k], s1 = ssrc[k + 1];
      float e0 = el[(size_t)s0 * 8 + hh] + erh;
      float e1 = el[(size_t)s1 * 8 + hh] + erh;
      e0 = e0 > 0.f ? e0 : SLOPE_ * e0;
      e1 = e1 > 0.f ? e1 : SLOPE_ * e1;
      u16x8 v0 = *(const u16x8*)&fs[(size_t)s0 * HD_ + lane * 8];
      u16x8 v1 = *(const u16x8*)&fs[(size_t)s1 * HD_ + lane * 8];
      float mm = fmaxf(e0, e1);
      if (mm > m) {
        float r = __expf(m - mm);
        s *= r;
#pragma unroll
        for (int j = 0; j < 8; ++j) acc[j] *= r;
        m = mm;
      }
      float x0 = __expf(e0 - m), x1 = __expf(e1 - m);
      s += x0 + x1;
#pragma unroll
      for (int j = 0; j < 8; ++j)
        acc[j] += x0 * bf2f((unsigned short)v0[j]) + x1 * bf2f((unsigned short)v1[j]);
    }
    if (k < r1) {
      int s0 = ssrc[k];
      float e0 = el[(size_t)s0 * 8 + hh] + erh;
      e0 = e0 > 0.f ? e0 : SLOPE_ * e0;
      u16x8 v0 = *(const u16x8*)&fs[(size_t)s0 * HD_ + lane * 8];
      if (e0 > m) {
        float r = __expf(m - e0);
        s *= r;
#pragma unroll
        for (int j = 0; j < 8; ++j) acc[j] *= r;
        m = e0;
      }
      float x0 = __expf(e0 - m);
      s += x0;
#pragma unroll
      for (int j = 0; j < 8; ++j) acc[j] += x0 * bf2f((unsigned short)v0[j]);
    }
    float inv = 1.f / s;
#pragma unroll
    for (int j = 0; j < 8; ++j) acc[j] *= inv;
  }
  u16x8 rv = *(const u16x8*)&res[(size_t)ln * HD_ + lane * 8];
  f32x4 o0, o1;
#pragma unroll
  for (int j = 0; j < 4; ++j) {
    o0[j] = acc[j] + bf2f((unsigned short)rv[j]);
    o1[j] = acc[4 + j] + bf2f((unsigned short)rv[4 + j]);
  }
  float* op = out + lane * 8;
  *(f32x4*)op = o0;
  *(f32x4*)(op + 4) = o1;
}

// =====================================================================================
extern "C" void kernel_launch(void* const* d_in, const int* in_sizes, int n_in,
                              void* d_out, int out_size, void* d_ws, size_t ws_size,
                              hipStream_t stream) {
  const float* h_user    = (const float*)d_in[0];
  const float* h_item    = (const float*)d_in[1];
  const int*   src_u2i   = (const int*)d_in[2];
  const int*   dst_u2i   = (const int*)d_in[3];
  const int*   src_i2u   = (const int*)d_in[4];
  const int*   dst_i2u   = (const int*)d_in[5];
  const float* W_src_u2i = (const float*)d_in[6];
  const float* W_dst_u2i = (const float*)d_in[7];
  const float* al_u2i    = (const float*)d_in[8];
  const float* ar_u2i    = (const float*)d_in[9];
  const float* bias_u2i  = (const float*)d_in[10];
  const float* W_res_u2i = (const float*)d_in[11];
  const float* W_src_i2u = (const float*)d_in[12];
  const float* W_dst_i2u = (const float*)d_in[13];
  const float* al_i2u    = (const float*)d_in[14];
  const float* ar_i2u    = (const float*)d_in[15];
  const float* bias_i2u  = (const float*)d_in[16];
  const float* W_res_i2u = (const float*)d_in[17];

  float* out_user = (float*)d_out;                       // [NU,512]
  float* out_item = (float*)d_out + (size_t)NU_ * HD_;   // [NI,512]

  char* ws = (char*)d_ws;
  size_t off = 0;
  auto take = [&](size_t bytes) -> char* {
    char* p = ws + off;
    off += (bytes + 255) & ~(size_t)255;
    return p;
  };
  unsigned short* fs_u2i   = (unsigned short*)take((size_t)NU_ * HD_ * 2);
  unsigned short* fs_i2u   = (unsigned short*)take((size_t)NI_ * HD_ * 2);
  unsigned short* res_user = (unsigned short*)take((size_t)NU_ * HD_ * 2);
  unsigned short* res_item = (unsigned short*)take((size_t)NI_ * HD_ * 2);
  unsigned short* hb_user  = (unsigned short*)take((size_t)MPAD_U * F_ * 2);
  unsigned short* hb_item  = (unsigned short*)take((size_t)MPAD_I * F_ * 2);
  // Wt: [0]=src_u2i [1]=res_u2i [2]=src_i2u [3]=res_i2u, each [512][256] bf16
  unsigned short* Wt  = (unsigned short*)take((size_t)4 * HD_ * F_ * 2);
  unsigned short* wfb = (unsigned short*)take((size_t)2 * 16 * F_ * 2);
  float* el_u2i = (float*)take((size_t)NU_ * 8 * 4);
  float* er_i2u = (float*)take((size_t)NU_ * 8 * 4);
  float* el_i2u = (float*)take((size_t)NI_ * 8 * 4);
  float* er_u2i = (float*)take((size_t)NI_ * 8 * 4);
  int* deg_all      = (int*)take((size_t)SCAN_N * 4);        // zeroed
  int* rowstart_all = (int*)take((size_t)(SCAN_N + 1) * 4);
  int* cursor_all   = (int*)take((size_t)SCAN_N * 4);
  int* bsum         = (int*)take((size_t)128 * 4);
  int* ssrc         = (int*)take((size_t)2 * NE_ * 4);

  hipMemsetAsync(deg_all, 0, (size_t)SCAN_N * 4, stream);

  // copy + wconv + folds + degree histogram (one launch)
  prep_kernel<<<PREP_NB, 256, 0, stream>>>(h_user, h_item,
                                           W_src_u2i, W_res_u2i, W_src_i2u, W_res_i2u,
                                           W_dst_u2i, W_dst_i2u,
                                           al_u2i, ar_u2i, al_i2u, ar_i2u,
                                           dst_u2i, dst_i2u,
                                           hb_user, hb_item, Wt, wfb, deg_all);

  // single-output GEMM tiles + el/er mini-tiles + scan_reduce tail
  gemm2_kernel<<<NT_ALL + EL_NB + SCAN_NB, 256, 0, stream>>>(
      hb_user, hb_item, Wt, wfb,
      fs_u2i, fs_i2u, res_user, res_item,
      bias_u2i, bias_i2u,
      el_u2i, er_i2u, el_i2u, er_u2i,
      deg_all, bsum);

  // CSR: scan + bin
  scan_apply_kernel<<<SCAN_NB, 256, 0, stream>>>(deg_all, bsum, rowstart_all, cursor_all);
  constexpr int EB2 = (2 * NE_ + 255) / 256;
  bin_kernel<<<EB2, 256, 0, stream>>>(src_u2i, dst_u2i, src_i2u, dst_i2u, cursor_all, ssrc);

  // fused online-softmax gather-accumulate + residual, write-only out
  accum_kernel<<<SCAN_N / 4, 256, 0, stream>>>(rowstart_all, ssrc,
                                               el_u2i, el_i2u, er_u2i, er_i2u,
                                               fs_u2i, fs_i2u, res_user, res_item,
                                               out_item, out_user);
}